// Round 1
// baseline (310.048 us; speedup 1.0000x reference)
//
#include <hip/hip_runtime.h>
#include <stdint.h>

#define NROWS 50000
#define KNB 16
#define DD 128
#define LN_EPS 1e-5f

typedef unsigned short ushort_t;
using frag_ab = __attribute__((ext_vector_type(8))) short;   // 8 bf16 (4 VGPRs)
using frag_cd = __attribute__((ext_vector_type(4))) float;   // 4 fp32 acc

static __device__ __forceinline__ float bf2f(uint32_t u) {
    union { uint32_t i; float f; } v; v.i = u << 16; return v.f;
}
static __device__ __forceinline__ ushort_t f2bf(float f) {
    union { float f; uint32_t i; } v; v.f = f;
    uint32_t x = v.i;
    return (ushort_t)((x + 0x7fffu + ((x >> 16) & 1u)) >> 16);
}
static __device__ __forceinline__ uint32_t packbf(float a, float b) {
    return (uint32_t)f2bf(a) | ((uint32_t)f2bf(b) << 16);
}
static __device__ __forceinline__ float leaky(float v) {
    return v > 0.0f ? v : 0.01f * v;
}
static __device__ __forceinline__ float tanh_fast(float z) {
    float e = __expf(2.0f * z);
    return 1.0f - 2.0f / (e + 1.0f);
}
// split fp32 -> (hi, lo) bf16 pair
static __device__ __forceinline__ void split_bf(float f, ushort_t& hi, ushort_t& lo) {
    hi = f2bf(f);
    lo = f2bf(f - bf2f(hi));
}

// R10-proven MFMA linear: out[r][j] = sum_d in[r][d]*W[j][d] + bias[j]
__global__ __launch_bounds__(256) void linear_mfma(
    const float* __restrict__ in, const float* __restrict__ W,
    const float* __restrict__ bias, float* __restrict__ out)
{
    __shared__ ushort_t Wl[128 * 136];
    const int tid = threadIdx.x;
    for (int i = tid; i < 128 * 64; i += 256) {
        int row = i >> 6, cp = (i & 63) << 1;
        float2 w = *(const float2*)(W + row * 128 + cp);
        *(uint32_t*)(&Wl[row * 136 + cp]) = packbf(w.x, w.y);
    }
    const int wv = tid >> 6, lane = tid & 63;
    const int quad = lane >> 4, lq = lane & 15;
    float bn[8];
    #pragma unroll
    for (int nt = 0; nt < 8; ++nt) bn[nt] = bias[nt * 16 + lq];
    __syncthreads();

    const int r0 = blockIdx.x * 64 + wv * 16;
    const int arow = r0 + lq;
    const int arc = arow < NROWS ? arow : NROWS - 1;

    frag_ab Ahi[4], Alo[4];
    const float* ip = in + (size_t)arc * DD + quad * 8;
    #pragma unroll
    for (int c = 0; c < 4; ++c) {
        float4 u = *(const float4*)(ip + c * 32);
        float4 v = *(const float4*)(ip + c * 32 + 4);
        float uu[8] = {u.x, u.y, u.z, u.w, v.x, v.y, v.z, v.w};
        #pragma unroll
        for (int i = 0; i < 8; ++i) {
            ushort_t h, l; split_bf(uu[i], h, l);
            Ahi[c][i] = (short)h; Alo[c][i] = (short)l;
        }
    }

    #pragma unroll
    for (int nt = 0; nt < 8; ++nt) {
        frag_cd acc = {0.f, 0.f, 0.f, 0.f};
        #pragma unroll
        for (int c = 0; c < 4; ++c) {
            frag_ab B = *(const frag_ab*)(&Wl[(nt * 16 + lq) * 136 + c * 32 + quad * 8]);
            acc = __builtin_amdgcn_mfma_f32_16x16x32_bf16(Alo[c], B, acc, 0, 0, 0);
            acc = __builtin_amdgcn_mfma_f32_16x16x32_bf16(Ahi[c], B, acc, 0, 0, 0);
        }
        #pragma unroll
        for (int r = 0; r < 4; ++r) {
            int orow = r0 + quad * 4 + r;
            if (orow < NROWS)
                out[(size_t)orow * DD + nt * 16 + lq] = acc[r] + bn[nt];
        }
    }
}

// Mega v3: 16 rows/iteration. Phase A = R9 attention (x4 per wave) -> a,m as
// hi/lo bf16 in LDS. Phase B = MFMA dual matvec, W1/W2 B-frags in registers.
// LN from hL. e_h ALIASES out: rows read in phase A, written in LN of the same
// iteration, barrier-separated; blocks own disjoint rows.
__global__ __launch_bounds__(256, 3) void mega_kernel(
    const float* e_h, const float* __restrict__ e_t,
    const int* __restrict__ topk_idx, const float* __restrict__ topk_w,
    const float* __restrict__ x,
    const float* __restrict__ W1, const float* __restrict__ b1,
    const float* __restrict__ W2, const float* __restrict__ b2,
    const float* __restrict__ gamma, const float* __restrict__ beta,
    float* out, int niters)
{
    __shared__ ushort_t aHi[16][136], aLo[16][136];   // row stride 272B (16B-aligned)
    __shared__ ushort_t mHi[16][136], mLo[16][136];
    __shared__ float hL[16][132];

    const int tid  = threadIdx.x;
    const int wv   = tid >> 6;
    const int lane = tid & 63;
    const int quad = lane >> 4, lq = lane & 15;
    const int n0   = wv * 32;   // this wave's 32 output columns

    // B-frags for W1/W2 (hi-only bf16), held in registers for the whole kernel:
    // B[k=quad*8+i][n=lq] = W[n0+t*16+lq][c*32+quad*8+i]
    frag_ab BW1[2][4], BW2[2][4];
    #pragma unroll
    for (int t = 0; t < 2; ++t) {
        const float* r1 = W1 + (size_t)(n0 + t * 16 + lq) * DD + quad * 8;
        const float* r2 = W2 + (size_t)(n0 + t * 16 + lq) * DD + quad * 8;
        #pragma unroll
        for (int c = 0; c < 4; ++c) {
            float4 u = *(const float4*)(r1 + c * 32);
            float4 v = *(const float4*)(r1 + c * 32 + 4);
            float uu[8] = {u.x, u.y, u.z, u.w, v.x, v.y, v.z, v.w};
            #pragma unroll
            for (int i = 0; i < 8; ++i) BW1[t][c][i] = (short)f2bf(uu[i]);
            float4 p = *(const float4*)(r2 + c * 32);
            float4 q = *(const float4*)(r2 + c * 32 + 4);
            float vv[8] = {p.x, p.y, p.z, p.w, q.x, q.y, q.z, q.w};
            #pragma unroll
            for (int i = 0; i < 8; ++i) BW2[t][c][i] = (short)f2bf(vv[i]);
        }
    }
    float b1v[2], b2v[2];
    #pragma unroll
    for (int t = 0; t < 2; ++t) {
        b1v[t] = b1[n0 + t * 16 + lq];
        b2v[t] = b2[n0 + t * 16 + lq];
    }
    const float g0 = gamma[lane], g1 = gamma[lane + 64];
    const float be0 = beta[lane], be1 = beta[lane + 64];

    for (int c = blockIdx.x; c < niters; c += gridDim.x) {
        const int r0 = c << 4;   // 16 rows per iteration (50000 = 16*3125)

        // ---- phase A: wave wv -> rows r0+4*wv+q; lane owns dims {2*lane, 2*lane+1} ----
        #pragma unroll
        for (int q = 0; q < 4; ++q) {
            const int lr = 4 * wv + q;
            const int nu = __builtin_amdgcn_readfirstlane(r0 + lr);
            int   tk[KNB];
            float pk[KNB];
            #pragma unroll
            for (int k = 0; k < KNB; ++k) tk[k] = topk_idx[nu * KNB + k];
            #pragma unroll
            for (int k = 0; k < KNB; ++k) pk[k] = topk_w[nu * KNB + k];
            float2 nb[KNB];
            #pragma unroll
            for (int k = 0; k < KNB; ++k) {
                int t = tk[k];
                t = ((unsigned)t < (unsigned)NROWS) ? t : 0;
                nb[k] = *(const float2*)(e_t + (size_t)t * DD + 2 * lane);
            }
            const float2 ehv = *(const float2*)(e_h + (size_t)nu * DD + 2 * lane);
            const float2 xv  = *(const float2*)(x   + (size_t)nu * DD + 2 * lane);

            float s[KNB];
            #pragma unroll
            for (int k = 0; k < KNB; ++k) {
                const float p = pk[k];
                const float er0 = ehv.x + p * (nb[k].x - ehv.x);
                const float er1 = ehv.y + p * (nb[k].y - ehv.y);
                float part = nb[k].x * tanh_fast(ehv.x + er0)
                           + nb[k].y * tanh_fast(ehv.y + er1);
                #pragma unroll
                for (int off = 32; off >= 1; off >>= 1)
                    part += __shfl_xor(part, off, 64);
                s[k] = part;
            }
            float mx = s[0];
            #pragma unroll
            for (int k = 1; k < KNB; ++k) mx = fmaxf(mx, s[k]);
            float sum = 0.0f;
            #pragma unroll
            for (int k = 0; k < KNB; ++k) { s[k] = __expf(s[k] - mx); sum += s[k]; }
            const float inv = 1.0f / sum;
            float e0 = 0.0f, e1 = 0.0f;
            #pragma unroll
            for (int k = 0; k < KNB; ++k) { e0 += s[k] * nb[k].x; e1 += s[k] * nb[k].y; }
            e0 *= inv; e1 *= inv;

            const float a0 = xv.x + e0, a1 = xv.y + e1;
            const float m0 = xv.x * e0, m1 = xv.y * e1;
            ushort_t h0, l0, h1, l1;
            split_bf(a0, h0, l0); split_bf(a1, h1, l1);
            *(uint32_t*)(&aHi[lr][2 * lane]) = (uint32_t)h0 | ((uint32_t)h1 << 16);
            *(uint32_t*)(&aLo[lr][2 * lane]) = (uint32_t)l0 | ((uint32_t)l1 << 16);
            split_bf(m0, h0, l0); split_bf(m1, h1, l1);
            *(uint32_t*)(&mHi[lr][2 * lane]) = (uint32_t)h0 | ((uint32_t)h1 << 16);
            *(uint32_t*)(&mLo[lr][2 * lane]) = (uint32_t)l0 | ((uint32_t)l1 << 16);
        }
        __syncthreads();   // a/m staged for all 16 rows; e_h reads complete

        // ---- phase B: MFMA. A[m=lq][k], B in regs, D[m=quad*4+r][n=lq] ----
        {
            frag_cd aA0 = {0.f,0.f,0.f,0.f}, aA1 = {0.f,0.f,0.f,0.f};
            frag_cd aM0 = {0.f,0.f,0.f,0.f}, aM1 = {0.f,0.f,0.f,0.f};
            #pragma unroll
            for (int kc = 0; kc < 4; ++kc) {
                frag_ab Ah = *(const frag_ab*)(&aHi[lq][kc * 32 + quad * 8]);
                frag_ab Al = *(const frag_ab*)(&aLo[lq][kc * 32 + quad * 8]);
                frag_ab Mh = *(const frag_ab*)(&mHi[lq][kc * 32 + quad * 8]);
                frag_ab Ml = *(const frag_ab*)(&mLo[lq][kc * 32 + quad * 8]);
                aA0 = __builtin_amdgcn_mfma_f32_16x16x32_bf16(Al, BW1[0][kc], aA0, 0, 0, 0);
                aA0 = __builtin_amdgcn_mfma_f32_16x16x32_bf16(Ah, BW1[0][kc], aA0, 0, 0, 0);
                aA1 = __builtin_amdgcn_mfma_f32_16x16x32_bf16(Al, BW1[1][kc], aA1, 0, 0, 0);
                aA1 = __builtin_amdgcn_mfma_f32_16x16x32_bf16(Ah, BW1[1][kc], aA1, 0, 0, 0);
                aM0 = __builtin_amdgcn_mfma_f32_16x16x32_bf16(Ml, BW2[0][kc], aM0, 0, 0, 0);
                aM0 = __builtin_amdgcn_mfma_f32_16x16x32_bf16(Mh, BW2[0][kc], aM0, 0, 0, 0);
                aM1 = __builtin_amdgcn_mfma_f32_16x16x32_bf16(Ml, BW2[1][kc], aM1, 0, 0, 0);
                aM1 = __builtin_amdgcn_mfma_f32_16x16x32_bf16(Mh, BW2[1][kc], aM1, 0, 0, 0);
            }
            #pragma unroll
            for (int r = 0; r < 4; ++r) {
                const int row = quad * 4 + r;
                hL[row][n0 + lq]      = leaky(aA0[r] + b1v[0]) + leaky(aM0[r] + b2v[0]);
                hL[row][n0 + 16 + lq] = leaky(aA1[r] + b1v[1]) + leaky(aM1[r] + b2v[1]);
            }
        }
        __syncthreads();

        // ---- LN: wave wv -> rows 4*wv..4*wv+3; lane owns cols {lane, lane+64} ----
        #pragma unroll
        for (int q = 0; q < 4; ++q) {
            const int lr = 4 * wv + q;
            const float h0 = hL[lr][lane], h1 = hL[lr][lane + 64];
            float s = h0 + h1, qq = h0 * h0 + h1 * h1;
            #pragma unroll
            for (int off = 32; off >= 1; off >>= 1) {
                s  += __shfl_xor(s,  off, 64);
                qq += __shfl_xor(qq, off, 64);
            }
            const float mu  = s * (1.0f / DD);
            const float var = qq * (1.0f / DD) - mu * mu;
            const float rs  = rsqrtf(var + LN_EPS);
            out[(size_t)(r0 + lr) * DD + lane]      = (h0 - mu) * rs * g0 + be0;
            out[(size_t)(r0 + lr) * DD + lane + 64] = (h1 - mu) * rs * g1 + be1;
        }
        __syncthreads();   // protect LDS buffers before next iteration
    }
}

extern "C" void kernel_launch(void* const* d_in, const int* in_sizes, int n_in,
                              void* d_out, int out_size, void* d_ws, size_t ws_size,
                              hipStream_t stream) {
    const float* x      = (const float*)d_in[0];
    const float* ehi    = (const float*)d_in[1];
    const float* eti    = (const float*)d_in[2];
    const int*   tidx   = (const int*)d_in[3];
    const float* tw     = (const float*)d_in[4];
    const float* Wh     = (const float*)d_in[5];
    const float* bh     = (const float*)d_in[6];
    const float* Wt     = (const float*)d_in[7];
    const float* bt     = (const float*)d_in[8];
    const float* W1     = (const float*)d_in[9];
    const float* b1     = (const float*)d_in[10];
    const float* W2     = (const float*)d_in[11];
    const float* b2     = (const float*)d_in[12];
    const float* gamma  = (const float*)d_in[13];
    const float* beta   = (const float*)d_in[14];

    float* e_h = (float*)d_out;   // staged in fp32 output buffer (exact fit)
    float* e_t = (float*)d_ws;    // 25.6 MB of ws (proven)

    const int nblk = (NROWS + 63) / 64;   // 782

    linear_mfma<<<nblk, 256, 0, stream>>>(ehi, Wh, bh, e_h);
    linear_mfma<<<nblk, 256, 0, stream>>>(eti, Wt, bt, e_t);
    mega_kernel<<<625, 256, 0, stream>>>(e_h, e_t, tidx, tw, x,
                                         W1, b1, W2, b2, gamma, beta,
                                         (float*)d_out, NROWS / 16);
}

// Round 2
// 307.844 us; speedup vs baseline: 1.0072x; 1.0072x over previous
//
#include <hip/hip_runtime.h>
#include <stdint.h>

#define NROWS 50000
#define KNB 16
#define DD 128
#define LN_EPS 1e-5f

typedef unsigned short ushort_t;
using frag_ab = __attribute__((ext_vector_type(8))) short;   // 8 bf16 (4 VGPRs)
using frag_cd = __attribute__((ext_vector_type(4))) float;   // 4 fp32 acc

static __device__ __forceinline__ float bf2f(uint32_t u) {
    union { uint32_t i; float f; } v; v.i = u << 16; return v.f;
}
static __device__ __forceinline__ ushort_t f2bf(float f) {
    union { float f; uint32_t i; } v; v.f = f;
    uint32_t x = v.i;
    return (ushort_t)((x + 0x7fffu + ((x >> 16) & 1u)) >> 16);
}
static __device__ __forceinline__ uint32_t packbf(float a, float b) {
    return (uint32_t)f2bf(a) | ((uint32_t)f2bf(b) << 16);
}
static __device__ __forceinline__ float leaky(float v) {
    return v > 0.0f ? v : 0.01f * v;
}
static __device__ __forceinline__ float tanh_fast(float z) {
    float e = __expf(2.0f * z);
    return 1.0f - 2.0f / (e + 1.0f);
}
// split fp32 -> (hi, lo) bf16 pair
static __device__ __forceinline__ void split_bf(float f, ushort_t& hi, ushort_t& lo) {
    hi = f2bf(f);
    lo = f2bf(f - bf2f(hi));
}

// Fused dual linear: block < nblk does task A (ehi,Wh,bh->e_h), else task B
// (eti,Wt,bt->e_t). Body identical to the R10-proven linear_mfma.
__global__ __launch_bounds__(256) void linear_mfma2(
    const float* __restrict__ inA, const float* __restrict__ WA,
    const float* __restrict__ bA, float* __restrict__ outA,
    const float* __restrict__ inB, const float* __restrict__ WB,
    const float* __restrict__ bB, float* __restrict__ outB, int nblk)
{
    const int which = blockIdx.x >= nblk;
    const int bid   = which ? blockIdx.x - nblk : blockIdx.x;
    const float* in   = which ? inB : inA;
    const float* W    = which ? WB  : WA;
    const float* bias = which ? bB  : bA;
    float* out        = which ? outB : outA;

    __shared__ ushort_t Wl[128 * 136];
    const int tid = threadIdx.x;
    for (int i = tid; i < 128 * 64; i += 256) {
        int row = i >> 6, cp = (i & 63) << 1;
        float2 w = *(const float2*)(W + row * 128 + cp);
        *(uint32_t*)(&Wl[row * 136 + cp]) = packbf(w.x, w.y);
    }
    const int wv = tid >> 6, lane = tid & 63;
    const int quad = lane >> 4, lq = lane & 15;
    float bn[8];
    #pragma unroll
    for (int nt = 0; nt < 8; ++nt) bn[nt] = bias[nt * 16 + lq];
    __syncthreads();

    const int r0 = bid * 64 + wv * 16;
    const int arow = r0 + lq;
    const int arc = arow < NROWS ? arow : NROWS - 1;

    frag_ab Ahi[4], Alo[4];
    const float* ip = in + (size_t)arc * DD + quad * 8;
    #pragma unroll
    for (int c = 0; c < 4; ++c) {
        float4 u = *(const float4*)(ip + c * 32);
        float4 v = *(const float4*)(ip + c * 32 + 4);
        float uu[8] = {u.x, u.y, u.z, u.w, v.x, v.y, v.z, v.w};
        #pragma unroll
        for (int i = 0; i < 8; ++i) {
            ushort_t h, l; split_bf(uu[i], h, l);
            Ahi[c][i] = (short)h; Alo[c][i] = (short)l;
        }
    }

    #pragma unroll
    for (int nt = 0; nt < 8; ++nt) {
        frag_cd acc = {0.f, 0.f, 0.f, 0.f};
        #pragma unroll
        for (int c = 0; c < 4; ++c) {
            frag_ab B = *(const frag_ab*)(&Wl[(nt * 16 + lq) * 136 + c * 32 + quad * 8]);
            acc = __builtin_amdgcn_mfma_f32_16x16x32_bf16(Alo[c], B, acc, 0, 0, 0);
            acc = __builtin_amdgcn_mfma_f32_16x16x32_bf16(Ahi[c], B, acc, 0, 0, 0);
        }
        #pragma unroll
        for (int r = 0; r < 4; ++r) {
            int orow = r0 + quad * 4 + r;
            if (orow < NROWS)
                out[(size_t)orow * DD + nt * 16 + lq] = acc[r] + bn[nt];
        }
    }
}

// Mega v4: identical structure to v3; grid raised 625->1563 so residency is
// resource-limited (6 blocks/CU) instead of grid-limited (2.4 blocks/CU).
__global__ __launch_bounds__(256, 3) void mega_kernel(
    const float* e_h, const float* __restrict__ e_t,
    const int* __restrict__ topk_idx, const float* __restrict__ topk_w,
    const float* __restrict__ x,
    const float* __restrict__ W1, const float* __restrict__ b1,
    const float* __restrict__ W2, const float* __restrict__ b2,
    const float* __restrict__ gamma, const float* __restrict__ beta,
    float* out, int niters)
{
    __shared__ ushort_t aHi[16][136], aLo[16][136];   // row stride 272B (16B-aligned)
    __shared__ ushort_t mHi[16][136], mLo[16][136];
    __shared__ float hL[16][132];

    const int tid  = threadIdx.x;
    const int wv   = tid >> 6;
    const int lane = tid & 63;
    const int quad = lane >> 4, lq = lane & 15;
    const int n0   = wv * 32;   // this wave's 32 output columns

    // B-frags for W1/W2 (hi-only bf16), held in registers for the whole kernel:
    // B[k=quad*8+i][n=lq] = W[n0+t*16+lq][c*32+quad*8+i]
    frag_ab BW1[2][4], BW2[2][4];
    #pragma unroll
    for (int t = 0; t < 2; ++t) {
        const float* r1 = W1 + (size_t)(n0 + t * 16 + lq) * DD + quad * 8;
        const float* r2 = W2 + (size_t)(n0 + t * 16 + lq) * DD + quad * 8;
        #pragma unroll
        for (int c = 0; c < 4; ++c) {
            float4 u = *(const float4*)(r1 + c * 32);
            float4 v = *(const float4*)(r1 + c * 32 + 4);
            float uu[8] = {u.x, u.y, u.z, u.w, v.x, v.y, v.z, v.w};
            #pragma unroll
            for (int i = 0; i < 8; ++i) BW1[t][c][i] = (short)f2bf(uu[i]);
            float4 p = *(const float4*)(r2 + c * 32);
            float4 q = *(const float4*)(r2 + c * 32 + 4);
            float vv[8] = {p.x, p.y, p.z, p.w, q.x, q.y, q.z, q.w};
            #pragma unroll
            for (int i = 0; i < 8; ++i) BW2[t][c][i] = (short)f2bf(vv[i]);
        }
    }
    float b1v[2], b2v[2];
    #pragma unroll
    for (int t = 0; t < 2; ++t) {
        b1v[t] = b1[n0 + t * 16 + lq];
        b2v[t] = b2[n0 + t * 16 + lq];
    }
    const float g0 = gamma[lane], g1 = gamma[lane + 64];
    const float be0 = beta[lane], be1 = beta[lane + 64];

    for (int c = blockIdx.x; c < niters; c += gridDim.x) {
        const int r0 = c << 4;   // 16 rows per iteration (50000 = 16*3125)

        // ---- phase A: wave wv -> rows r0+4*wv+q; lane owns dims {2*lane, 2*lane+1} ----
        #pragma unroll
        for (int q = 0; q < 4; ++q) {
            const int lr = 4 * wv + q;
            const int nu = __builtin_amdgcn_readfirstlane(r0 + lr);
            int   tk[KNB];
            float pk[KNB];
            #pragma unroll
            for (int k = 0; k < KNB; ++k) tk[k] = topk_idx[nu * KNB + k];
            #pragma unroll
            for (int k = 0; k < KNB; ++k) pk[k] = topk_w[nu * KNB + k];
            float2 nb[KNB];
            #pragma unroll
            for (int k = 0; k < KNB; ++k) {
                int t = tk[k];
                t = ((unsigned)t < (unsigned)NROWS) ? t : 0;
                nb[k] = *(const float2*)(e_t + (size_t)t * DD + 2 * lane);
            }
            const float2 ehv = *(const float2*)(e_h + (size_t)nu * DD + 2 * lane);
            const float2 xv  = *(const float2*)(x   + (size_t)nu * DD + 2 * lane);

            // arg = e_h + eh_r = 2*e_h + p*(nb - e_h)
            const float e2x = ehv.x + ehv.x, e2y = ehv.y + ehv.y;

            float s[KNB];
            #pragma unroll
            for (int k = 0; k < KNB; ++k) {
                const float p = pk[k];
                const float ax = __builtin_fmaf(p, nb[k].x - ehv.x, e2x);
                const float ay = __builtin_fmaf(p, nb[k].y - ehv.y, e2y);
                float part = nb[k].x * tanh_fast(ax)
                           + nb[k].y * tanh_fast(ay);
                #pragma unroll
                for (int off = 32; off >= 1; off >>= 1)
                    part += __shfl_xor(part, off, 64);
                s[k] = part;
            }
            float mx = s[0];
            #pragma unroll
            for (int k = 1; k < KNB; ++k) mx = fmaxf(mx, s[k]);
            float sum = 0.0f;
            #pragma unroll
            for (int k = 0; k < KNB; ++k) { s[k] = __expf(s[k] - mx); sum += s[k]; }
            const float inv = 1.0f / sum;
            float e0 = 0.0f, e1 = 0.0f;
            #pragma unroll
            for (int k = 0; k < KNB; ++k) { e0 += s[k] * nb[k].x; e1 += s[k] * nb[k].y; }
            e0 *= inv; e1 *= inv;

            const float a0 = xv.x + e0, a1 = xv.y + e1;
            const float m0 = xv.x * e0, m1 = xv.y * e1;
            ushort_t h0, l0, h1, l1;
            split_bf(a0, h0, l0); split_bf(a1, h1, l1);
            *(uint32_t*)(&aHi[lr][2 * lane]) = (uint32_t)h0 | ((uint32_t)h1 << 16);
            *(uint32_t*)(&aLo[lr][2 * lane]) = (uint32_t)l0 | ((uint32_t)l1 << 16);
            split_bf(m0, h0, l0); split_bf(m1, h1, l1);
            *(uint32_t*)(&mHi[lr][2 * lane]) = (uint32_t)h0 | ((uint32_t)h1 << 16);
            *(uint32_t*)(&mLo[lr][2 * lane]) = (uint32_t)l0 | ((uint32_t)l1 << 16);
        }
        __syncthreads();   // a/m staged for all 16 rows; e_h reads complete

        // ---- phase B: MFMA. A[m=lq][k], B in regs, D[m=quad*4+r][n=lq] ----
        {
            frag_cd aA0 = {0.f,0.f,0.f,0.f}, aA1 = {0.f,0.f,0.f,0.f};
            frag_cd aM0 = {0.f,0.f,0.f,0.f}, aM1 = {0.f,0.f,0.f,0.f};
            #pragma unroll
            for (int kc = 0; kc < 4; ++kc) {
                frag_ab Ah = *(const frag_ab*)(&aHi[lq][kc * 32 + quad * 8]);
                frag_ab Al = *(const frag_ab*)(&aLo[lq][kc * 32 + quad * 8]);
                frag_ab Mh = *(const frag_ab*)(&mHi[lq][kc * 32 + quad * 8]);
                frag_ab Ml = *(const frag_ab*)(&mLo[lq][kc * 32 + quad * 8]);
                aA0 = __builtin_amdgcn_mfma_f32_16x16x32_bf16(Al, BW1[0][kc], aA0, 0, 0, 0);
                aA0 = __builtin_amdgcn_mfma_f32_16x16x32_bf16(Ah, BW1[0][kc], aA0, 0, 0, 0);
                aA1 = __builtin_amdgcn_mfma_f32_16x16x32_bf16(Al, BW1[1][kc], aA1, 0, 0, 0);
                aA1 = __builtin_amdgcn_mfma_f32_16x16x32_bf16(Ah, BW1[1][kc], aA1, 0, 0, 0);
                aM0 = __builtin_amdgcn_mfma_f32_16x16x32_bf16(Ml, BW2[0][kc], aM0, 0, 0, 0);
                aM0 = __builtin_amdgcn_mfma_f32_16x16x32_bf16(Mh, BW2[0][kc], aM0, 0, 0, 0);
                aM1 = __builtin_amdgcn_mfma_f32_16x16x32_bf16(Ml, BW2[1][kc], aM1, 0, 0, 0);
                aM1 = __builtin_amdgcn_mfma_f32_16x16x32_bf16(Mh, BW2[1][kc], aM1, 0, 0, 0);
            }
            #pragma unroll
            for (int r = 0; r < 4; ++r) {
                const int row = quad * 4 + r;
                hL[row][n0 + lq]      = leaky(aA0[r] + b1v[0]) + leaky(aM0[r] + b2v[0]);
                hL[row][n0 + 16 + lq] = leaky(aA1[r] + b1v[1]) + leaky(aM1[r] + b2v[1]);
            }
        }
        __syncthreads();

        // ---- LN: wave wv -> rows 4*wv..4*wv+3; lane owns cols {lane, lane+64} ----
        #pragma unroll
        for (int q = 0; q < 4; ++q) {
            const int lr = 4 * wv + q;
            const float h0 = hL[lr][lane], h1 = hL[lr][lane + 64];
            float s = h0 + h1, qq = h0 * h0 + h1 * h1;
            #pragma unroll
            for (int off = 32; off >= 1; off >>= 1) {
                s  += __shfl_xor(s,  off, 64);
                qq += __shfl_xor(qq, off, 64);
            }
            const float mu  = s * (1.0f / DD);
            const float var = qq * (1.0f / DD) - mu * mu;
            const float rs  = rsqrtf(var + LN_EPS);
            out[(size_t)(r0 + lr) * DD + lane]      = (h0 - mu) * rs * g0 + be0;
            out[(size_t)(r0 + lr) * DD + lane + 64] = (h1 - mu) * rs * g1 + be1;
        }
        __syncthreads();   // protect LDS buffers before next iteration
    }
}

extern "C" void kernel_launch(void* const* d_in, const int* in_sizes, int n_in,
                              void* d_out, int out_size, void* d_ws, size_t ws_size,
                              hipStream_t stream) {
    const float* x      = (const float*)d_in[0];
    const float* ehi    = (const float*)d_in[1];
    const float* eti    = (const float*)d_in[2];
    const int*   tidx   = (const int*)d_in[3];
    const float* tw     = (const float*)d_in[4];
    const float* Wh     = (const float*)d_in[5];
    const float* bh     = (const float*)d_in[6];
    const float* Wt     = (const float*)d_in[7];
    const float* bt     = (const float*)d_in[8];
    const float* W1     = (const float*)d_in[9];
    const float* b1     = (const float*)d_in[10];
    const float* W2     = (const float*)d_in[11];
    const float* b2     = (const float*)d_in[12];
    const float* gamma  = (const float*)d_in[13];
    const float* beta   = (const float*)d_in[14];

    float* e_h = (float*)d_out;   // staged in fp32 output buffer (exact fit)
    float* e_t = (float*)d_ws;    // 25.6 MB of ws (proven)

    const int nblk = (NROWS + 63) / 64;   // 782

    linear_mfma2<<<2 * nblk, 256, 0, stream>>>(ehi, Wh, bh, e_h,
                                               eti, Wt, bt, e_t, nblk);
    mega_kernel<<<1563, 256, 0, stream>>>(e_h, e_t, tidx, tw, x,
                                          W1, b1, W2, b2, gamma, beta,
                                          (float*)d_out, NROWS / 16);
}

// Round 3
// 269.771 us; speedup vs baseline: 1.1493x; 1.1411x over previous
//
#include <hip/hip_runtime.h>
#include <stdint.h>

#define NROWS 50000
#define KNB 16
#define DD 128
#define LN_EPS 1e-5f

typedef unsigned short ushort_t;
using frag_ab = __attribute__((ext_vector_type(8))) short;   // 8 bf16 (4 VGPRs)
using frag_cd = __attribute__((ext_vector_type(4))) float;   // 4 fp32 acc

static __device__ __forceinline__ float bf2f(uint32_t u) {
    union { uint32_t i; float f; } v; v.i = u << 16; return v.f;
}
static __device__ __forceinline__ ushort_t f2bf(float f) {
    union { float f; uint32_t i; } v; v.f = f;
    uint32_t x = v.i;
    return (ushort_t)((x + 0x7fffu + ((x >> 16) & 1u)) >> 16);
}
static __device__ __forceinline__ uint32_t packbf(float a, float b) {
    return (uint32_t)f2bf(a) | ((uint32_t)f2bf(b) << 16);
}
static __device__ __forceinline__ float leaky(float v) {
    return v > 0.0f ? v : 0.01f * v;
}
static __device__ __forceinline__ float tanh_fast(float z) {
    float e = __expf(2.0f * z);
    return 1.0f - 2.0f / (e + 1.0f);
}
// split fp32 -> (hi, lo) bf16 pair
static __device__ __forceinline__ void split_bf(float f, ushort_t& hi, ushort_t& lo) {
    hi = f2bf(f);
    lo = f2bf(f - bf2f(hi));
}
// packed f32x2 -> bf16x2 (RNE), single HW instr
static __device__ __forceinline__ uint32_t cvtpk(float lo, float hi) {
    uint32_t r;
    asm("v_cvt_pk_bf16_f32 %0, %1, %2" : "=v"(r) : "v"(lo), "v"(hi));
    return r;
}
// load 8 consecutive f32 of a W row -> bf16 frag (RNE, identical to f2bf)
static __device__ __forceinline__ frag_ab load_wfrag(const float* wp) {
    float4 u = *(const float4*)(wp);
    float4 v = *(const float4*)(wp + 4);
    union { uint32_t d[4]; frag_ab f; } r;
    r.d[0] = cvtpk(u.x, u.y);
    r.d[1] = cvtpk(u.z, u.w);
    r.d[2] = cvtpk(v.x, v.y);
    r.d[3] = cvtpk(v.z, v.w);
    return r.f;
}

// Fused dual linear: block < nblk does task A (ehi,Wh,bh->e_h), else task B
// (eti,Wt,bt->e_t). Body identical to the R10-proven linear_mfma.
__global__ __launch_bounds__(256) void linear_mfma2(
    const float* __restrict__ inA, const float* __restrict__ WA,
    const float* __restrict__ bA, float* __restrict__ outA,
    const float* __restrict__ inB, const float* __restrict__ WB,
    const float* __restrict__ bB, float* __restrict__ outB, int nblk)
{
    const int which = blockIdx.x >= nblk;
    const int bid   = which ? blockIdx.x - nblk : blockIdx.x;
    const float* in   = which ? inB : inA;
    const float* W    = which ? WB  : WA;
    const float* bias = which ? bB  : bA;
    float* out        = which ? outB : outA;

    __shared__ ushort_t Wl[128 * 136];
    const int tid = threadIdx.x;
    for (int i = tid; i < 128 * 64; i += 256) {
        int row = i >> 6, cp = (i & 63) << 1;
        float2 w = *(const float2*)(W + row * 128 + cp);
        *(uint32_t*)(&Wl[row * 136 + cp]) = packbf(w.x, w.y);
    }
    const int wv = tid >> 6, lane = tid & 63;
    const int quad = lane >> 4, lq = lane & 15;
    float bn[8];
    #pragma unroll
    for (int nt = 0; nt < 8; ++nt) bn[nt] = bias[nt * 16 + lq];
    __syncthreads();

    const int r0 = bid * 64 + wv * 16;
    const int arow = r0 + lq;
    const int arc = arow < NROWS ? arow : NROWS - 1;

    frag_ab Ahi[4], Alo[4];
    const float* ip = in + (size_t)arc * DD + quad * 8;
    #pragma unroll
    for (int c = 0; c < 4; ++c) {
        float4 u = *(const float4*)(ip + c * 32);
        float4 v = *(const float4*)(ip + c * 32 + 4);
        float uu[8] = {u.x, u.y, u.z, u.w, v.x, v.y, v.z, v.w};
        #pragma unroll
        for (int i = 0; i < 8; ++i) {
            ushort_t h, l; split_bf(uu[i], h, l);
            Ahi[c][i] = (short)h; Alo[c][i] = (short)l;
        }
    }

    #pragma unroll
    for (int nt = 0; nt < 8; ++nt) {
        frag_cd acc = {0.f, 0.f, 0.f, 0.f};
        #pragma unroll
        for (int c = 0; c < 4; ++c) {
            frag_ab B = *(const frag_ab*)(&Wl[(nt * 16 + lq) * 136 + c * 32 + quad * 8]);
            acc = __builtin_amdgcn_mfma_f32_16x16x32_bf16(Alo[c], B, acc, 0, 0, 0);
            acc = __builtin_amdgcn_mfma_f32_16x16x32_bf16(Ahi[c], B, acc, 0, 0, 0);
        }
        #pragma unroll
        for (int r = 0; r < 4; ++r) {
            int orow = r0 + quad * 4 + r;
            if (orow < NROWS)
                out[(size_t)orow * DD + nt * 16 + lq] = acc[r] + bn[nt];
        }
    }
}

// Mega v5: W1/W2 B-frags are NO LONGER persistent registers — they are
// re-loaded from global (L1/L2-hot) inside each iteration and converted with
// v_cvt_pk_bf16_f32. W1/W2 are deliberately NOT __restrict__ so the out-stores
// may alias them -> compiler cannot hoist the loads out of the loop -> peak
// unified VGPR+AGPR footprint drops below 128 -> 4 waves/SIMD instead of 2.
__global__ __launch_bounds__(256, 4) void mega_kernel(
    const float* e_h, const float* __restrict__ e_t,
    const int* __restrict__ topk_idx, const float* __restrict__ topk_w,
    const float* __restrict__ x,
    const float* W1, const float* __restrict__ b1,
    const float* W2, const float* __restrict__ b2,
    const float* __restrict__ gamma, const float* __restrict__ beta,
    float* out, int niters)
{
    __shared__ ushort_t aHi[16][136], aLo[16][136];   // row stride 272B (16B-aligned)
    __shared__ ushort_t mHi[16][136], mLo[16][136];
    __shared__ float hL[16][132];

    const int tid  = threadIdx.x;
    const int wv   = tid >> 6;
    const int lane = tid & 63;
    const int quad = lane >> 4, lq = lane & 15;
    const int n0   = wv * 32;   // this wave's 32 output columns

    float b1v[2], b2v[2];
    #pragma unroll
    for (int t = 0; t < 2; ++t) {
        b1v[t] = b1[n0 + t * 16 + lq];
        b2v[t] = b2[n0 + t * 16 + lq];
    }
    const float g0 = gamma[lane], g1 = gamma[lane + 64];
    const float be0 = beta[lane], be1 = beta[lane + 64];

    // per-lane W row base: row n0+lq (t=0); +16*DD for t=1
    const float* w1p = W1 + (size_t)(n0 + lq) * DD + quad * 8;
    const float* w2p = W2 + (size_t)(n0 + lq) * DD + quad * 8;

    for (int c = blockIdx.x; c < niters; c += gridDim.x) {
        const int r0 = c << 4;   // 16 rows per iteration (50000 = 16*3125)

        // ---- phase A: wave wv -> rows r0+4*wv+q; lane owns dims {2*lane, 2*lane+1} ----
        #pragma unroll
        for (int q = 0; q < 4; ++q) {
            const int lr = 4 * wv + q;
            const int nu = __builtin_amdgcn_readfirstlane(r0 + lr);
            int   tk[KNB];
            float pk[KNB];
            #pragma unroll
            for (int k = 0; k < KNB; ++k) tk[k] = topk_idx[nu * KNB + k];
            #pragma unroll
            for (int k = 0; k < KNB; ++k) pk[k] = topk_w[nu * KNB + k];
            float2 nb[KNB];
            #pragma unroll
            for (int k = 0; k < KNB; ++k) {
                int t = tk[k];
                t = ((unsigned)t < (unsigned)NROWS) ? t : 0;
                nb[k] = *(const float2*)(e_t + (size_t)t * DD + 2 * lane);
            }
            const float2 ehv = *(const float2*)(e_h + (size_t)nu * DD + 2 * lane);
            const float2 xv  = *(const float2*)(x   + (size_t)nu * DD + 2 * lane);

            // arg = e_h + eh_r = 2*e_h + p*(nb - e_h)
            const float e2x = ehv.x + ehv.x, e2y = ehv.y + ehv.y;

            float s[KNB];
            #pragma unroll
            for (int k = 0; k < KNB; ++k) {
                const float p = pk[k];
                const float ax = __builtin_fmaf(p, nb[k].x - ehv.x, e2x);
                const float ay = __builtin_fmaf(p, nb[k].y - ehv.y, e2y);
                float part = nb[k].x * tanh_fast(ax)
                           + nb[k].y * tanh_fast(ay);
                #pragma unroll
                for (int off = 32; off >= 1; off >>= 1)
                    part += __shfl_xor(part, off, 64);
                s[k] = part;
            }
            float mx = s[0];
            #pragma unroll
            for (int k = 1; k < KNB; ++k) mx = fmaxf(mx, s[k]);
            float sum = 0.0f;
            #pragma unroll
            for (int k = 0; k < KNB; ++k) { s[k] = __expf(s[k] - mx); sum += s[k]; }
            const float inv = 1.0f / sum;
            float e0 = 0.0f, e1 = 0.0f;
            #pragma unroll
            for (int k = 0; k < KNB; ++k) { e0 += s[k] * nb[k].x; e1 += s[k] * nb[k].y; }
            e0 *= inv; e1 *= inv;

            const float a0 = xv.x + e0, a1 = xv.y + e1;
            const float m0 = xv.x * e0, m1 = xv.y * e1;
            ushort_t h0, l0, h1, l1;
            split_bf(a0, h0, l0); split_bf(a1, h1, l1);
            *(uint32_t*)(&aHi[lr][2 * lane]) = (uint32_t)h0 | ((uint32_t)h1 << 16);
            *(uint32_t*)(&aLo[lr][2 * lane]) = (uint32_t)l0 | ((uint32_t)l1 << 16);
            split_bf(m0, h0, l0); split_bf(m1, h1, l1);
            *(uint32_t*)(&mHi[lr][2 * lane]) = (uint32_t)h0 | ((uint32_t)h1 << 16);
            *(uint32_t*)(&mLo[lr][2 * lane]) = (uint32_t)l0 | ((uint32_t)l1 << 16);
        }
        __syncthreads();   // a/m staged for all 16 rows; e_h reads complete

        // ---- phase B: MFMA. A[m=lq][k] from LDS, B loaded per-kc from global ----
        {
            frag_cd aA0 = {0.f,0.f,0.f,0.f}, aA1 = {0.f,0.f,0.f,0.f};
            frag_cd aM0 = {0.f,0.f,0.f,0.f}, aM1 = {0.f,0.f,0.f,0.f};
            #pragma unroll
            for (int kc = 0; kc < 4; ++kc) {
                frag_ab B10 = load_wfrag(w1p + kc * 32);
                frag_ab B11 = load_wfrag(w1p + 16 * DD + kc * 32);
                frag_ab B20 = load_wfrag(w2p + kc * 32);
                frag_ab B21 = load_wfrag(w2p + 16 * DD + kc * 32);
                frag_ab Ah = *(const frag_ab*)(&aHi[lq][kc * 32 + quad * 8]);
                frag_ab Al = *(const frag_ab*)(&aLo[lq][kc * 32 + quad * 8]);
                frag_ab Mh = *(const frag_ab*)(&mHi[lq][kc * 32 + quad * 8]);
                frag_ab Ml = *(const frag_ab*)(&mLo[lq][kc * 32 + quad * 8]);
                aA0 = __builtin_amdgcn_mfma_f32_16x16x32_bf16(Al, B10, aA0, 0, 0, 0);
                aA0 = __builtin_amdgcn_mfma_f32_16x16x32_bf16(Ah, B10, aA0, 0, 0, 0);
                aA1 = __builtin_amdgcn_mfma_f32_16x16x32_bf16(Al, B11, aA1, 0, 0, 0);
                aA1 = __builtin_amdgcn_mfma_f32_16x16x32_bf16(Ah, B11, aA1, 0, 0, 0);
                aM0 = __builtin_amdgcn_mfma_f32_16x16x32_bf16(Ml, B20, aM0, 0, 0, 0);
                aM0 = __builtin_amdgcn_mfma_f32_16x16x32_bf16(Mh, B20, aM0, 0, 0, 0);
                aM1 = __builtin_amdgcn_mfma_f32_16x16x32_bf16(Ml, B21, aM1, 0, 0, 0);
                aM1 = __builtin_amdgcn_mfma_f32_16x16x32_bf16(Mh, B21, aM1, 0, 0, 0);
            }
            #pragma unroll
            for (int r = 0; r < 4; ++r) {
                const int row = quad * 4 + r;
                hL[row][n0 + lq]      = leaky(aA0[r] + b1v[0]) + leaky(aM0[r] + b2v[0]);
                hL[row][n0 + 16 + lq] = leaky(aA1[r] + b1v[1]) + leaky(aM1[r] + b2v[1]);
            }
        }
        __syncthreads();

        // ---- LN: wave wv -> rows 4*wv..4*wv+3; lane owns cols {lane, lane+64} ----
        #pragma unroll
        for (int q = 0; q < 4; ++q) {
            const int lr = 4 * wv + q;
            const float h0 = hL[lr][lane], h1 = hL[lr][lane + 64];
            float s = h0 + h1, qq = h0 * h0 + h1 * h1;
            #pragma unroll
            for (int off = 32; off >= 1; off >>= 1) {
                s  += __shfl_xor(s,  off, 64);
                qq += __shfl_xor(qq, off, 64);
            }
            const float mu  = s * (1.0f / DD);
            const float var = qq * (1.0f / DD) - mu * mu;
            const float rs  = rsqrtf(var + LN_EPS);
            out[(size_t)(r0 + lr) * DD + lane]      = (h0 - mu) * rs * g0 + be0;
            out[(size_t)(r0 + lr) * DD + lane + 64] = (h1 - mu) * rs * g1 + be1;
        }
        __syncthreads();   // protect LDS buffers before next iteration
    }
}

extern "C" void kernel_launch(void* const* d_in, const int* in_sizes, int n_in,
                              void* d_out, int out_size, void* d_ws, size_t ws_size,
                              hipStream_t stream) {
    const float* x      = (const float*)d_in[0];
    const float* ehi    = (const float*)d_in[1];
    const float* eti    = (const float*)d_in[2];
    const int*   tidx   = (const int*)d_in[3];
    const float* tw     = (const float*)d_in[4];
    const float* Wh     = (const float*)d_in[5];
    const float* bh     = (const float*)d_in[6];
    const float* Wt     = (const float*)d_in[7];
    const float* bt     = (const float*)d_in[8];
    const float* W1     = (const float*)d_in[9];
    const float* b1     = (const float*)d_in[10];
    const float* W2     = (const float*)d_in[11];
    const float* b2     = (const float*)d_in[12];
    const float* gamma  = (const float*)d_in[13];
    const float* beta   = (const float*)d_in[14];

    float* e_h = (float*)d_out;   // staged in fp32 output buffer (exact fit)
    float* e_t = (float*)d_ws;    // 25.6 MB of ws (proven)

    const int nblk = (NROWS + 63) / 64;   // 782

    linear_mfma2<<<2 * nblk, 256, 0, stream>>>(ehi, Wh, bh, e_h,
                                               eti, Wt, bt, e_t, nblk);
    mega_kernel<<<1024, 256, 0, stream>>>(e_h, e_t, tidx, tw, x,
                                          W1, b1, W2, b2, gamma, beta,
                                          (float*)d_out, NROWS / 16);
}